// Round 1
// baseline (137.727 us; speedup 1.0000x reference)
//
#include <hip/hip_runtime.h>
#include <math.h>

// Problem constants (from the reference)
#define NN 4096
#define DD 512
#define PP 8
#define QQ 32
#define NB_TOT (PP + QQ)          // 40 neighbors per anchor
constexpr float MARGIN = 1.0f;
constexpr float L2W    = 0.005f;
constexpr float EPS    = 1e-6f;

__global__ void init_out_kernel(float* out) {
    if (threadIdx.x == 0) out[0] = 0.0f;
}

__device__ inline float wave_reduce_sum(float v) {
    // full 64-lane butterfly reduce
    v += __shfl_xor(v, 32, 64);
    v += __shfl_xor(v, 16, 64);
    v += __shfl_xor(v,  8, 64);
    v += __shfl_xor(v,  4, 64);
    v += __shfl_xor(v,  2, 64);
    v += __shfl_xor(v,  1, 64);
    return v;
}

__global__ __launch_bounds__(256) void triplet_crit_kernel(
    const float* __restrict__ batch,
    const int*   __restrict__ anchors,
    const int*   __restrict__ pos_idx,
    const int*   __restrict__ neg_idx,
    float*       __restrict__ out)
{
    const int i    = blockIdx.x;     // anchor / batch row handled by this block
    const int tid  = threadIdx.x;
    const int lane = tid & 63;
    const int wave = tid >> 6;       // 0..3

    __shared__ float dist[NB_TOT];   // 40 distances
    __shared__ float norm_sh;        // ||batch[i]||

    // ---- load anchor row: lane holds 8 contiguous floats (2x float4) ----
    const int arow = anchors[i];
    const float* __restrict__ arowp = batch + (size_t)arow * DD + lane * 8;
    const float4 a0 = *reinterpret_cast<const float4*>(arowp);
    const float4 a1 = *reinterpret_cast<const float4*>(arowp + 4);

    // ---- wave 0 also computes ||batch[i]|| for the L2 regularizer ----
    if (wave == 0) {
        const float* __restrict__ rp = batch + (size_t)i * DD + lane * 8;
        const float4 r0 = *reinterpret_cast<const float4*>(rp);
        const float4 r1 = *reinterpret_cast<const float4*>(rp + 4);
        float s = r0.x*r0.x + r0.y*r0.y + r0.z*r0.z + r0.w*r0.w
                + r1.x*r1.x + r1.y*r1.y + r1.z*r1.z + r1.w*r1.w;
        s = wave_reduce_sum(s);
        if (lane == 0) norm_sh = sqrtf(s);
    }

    // ---- waves stripe over the 40 neighbors ----
    for (int j = wave; j < NB_TOT; j += 4) {
        const int nidx = (j < PP) ? pos_idx[i * PP + j]
                                  : neg_idx[i * QQ + (j - PP)];
        const float* __restrict__ brp = batch + (size_t)nidx * DD + lane * 8;
        const float4 b0 = *reinterpret_cast<const float4*>(brp);
        const float4 b1 = *reinterpret_cast<const float4*>(brp + 4);

        float d, s = 0.0f;
        d = a0.x - b0.x + EPS; s += d * d;
        d = a0.y - b0.y + EPS; s += d * d;
        d = a0.z - b0.z + EPS; s += d * d;
        d = a0.w - b0.w + EPS; s += d * d;
        d = a1.x - b1.x + EPS; s += d * d;
        d = a1.y - b1.y + EPS; s += d * d;
        d = a1.z - b1.z + EPS; s += d * d;
        d = a1.w - b1.w + EPS; s += d * d;

        s = wave_reduce_sum(s);
        if (lane == 0) dist[j] = sqrtf(s);
    }

    __syncthreads();

    // ---- thread 0: two small logsumexps + relu + block contribution ----
    if (tid == 0) {
        // pos_term = logsumexp(dist[0..8))
        float m = dist[0];
        #pragma unroll
        for (int p = 1; p < PP; ++p) m = fmaxf(m, dist[p]);
        float se = 0.0f;
        #pragma unroll
        for (int p = 0; p < PP; ++p) se += expf(dist[p] - m);
        const float pos_term = m + logf(se);

        // neg_term = logsumexp(MARGIN - dist[8..40))
        float mn = MARGIN - dist[PP];
        #pragma unroll
        for (int q = 1; q < QQ; ++q) mn = fmaxf(mn, MARGIN - dist[PP + q]);
        float se2 = 0.0f;
        #pragma unroll
        for (int q = 0; q < QQ; ++q) se2 += expf(MARGIN - dist[PP + q] - mn);
        const float neg_term = mn + logf(se2);

        const float per = fmaxf(0.0f, pos_term + neg_term);
        // out = mean(per) + L2W * mean(norm)  ->  sum of (per + L2W*norm)/N
        const float contrib = (per + L2W * norm_sh) * (1.0f / (float)NN);
        atomicAdd(out, contrib);
    }
}

extern "C" void kernel_launch(void* const* d_in, const int* in_sizes, int n_in,
                              void* d_out, int out_size, void* d_ws, size_t ws_size,
                              hipStream_t stream) {
    const float* batch   = (const float*)d_in[0];
    const int*   anchors = (const int*)d_in[1];
    const int*   pos_idx = (const int*)d_in[2];
    const int*   neg_idx = (const int*)d_in[3];
    float*       out     = (float*)d_out;

    init_out_kernel<<<1, 1, 0, stream>>>(out);
    triplet_crit_kernel<<<NN, 256, 0, stream>>>(batch, anchors, pos_idx, neg_idx, out);
}

// Round 2
// 91.739 us; speedup vs baseline: 1.5013x; 1.5013x over previous
//
#include <hip/hip_runtime.h>
#include <math.h>
#include <float.h>

// Problem constants (from the reference)
#define NN 4096
#define DD 512
#define PP 8
#define QQ 32
#define NB_TOT (PP + QQ)          // 40 neighbors per anchor
#define PER_WAVE (NB_TOT / 4)     // 10 neighbors per wave
constexpr float MARGIN = 1.0f;
constexpr float L2W    = 0.005f;
constexpr float EPS    = 1e-6f;

__device__ inline float wave_reduce_sum(float v) {
    v += __shfl_xor(v, 32, 64);
    v += __shfl_xor(v, 16, 64);
    v += __shfl_xor(v,  8, 64);
    v += __shfl_xor(v,  4, 64);
    v += __shfl_xor(v,  2, 64);
    v += __shfl_xor(v,  1, 64);
    return v;
}

__device__ inline float wave_reduce_max(float v) {
    v = fmaxf(v, __shfl_xor(v, 32, 64));
    v = fmaxf(v, __shfl_xor(v, 16, 64));
    v = fmaxf(v, __shfl_xor(v,  8, 64));
    v = fmaxf(v, __shfl_xor(v,  4, 64));
    v = fmaxf(v, __shfl_xor(v,  2, 64));
    v = fmaxf(v, __shfl_xor(v,  1, 64));
    return v;
}

// One block per anchor. 4 waves; each wave owns 10 neighbors with all 10 row
// loads in flight (MLP) before any reduction. Per-anchor result -> ws[i].
__global__ __launch_bounds__(256) void dist_kernel(
    const float* __restrict__ batch,
    const int*   __restrict__ anchors,
    const int*   __restrict__ pos_idx,
    const int*   __restrict__ neg_idx,
    float*       __restrict__ ws)
{
    const int i    = blockIdx.x;
    const int tid  = threadIdx.x;
    const int lane = tid & 63;
    const int wave = tid >> 6;       // 0..3

    __shared__ float dist[NB_TOT];
    __shared__ float norm_sh;

    // ---- anchor row: lane holds 8 contiguous floats ----
    const int arow = anchors[i];
    const float* __restrict__ ap = batch + (size_t)arow * DD + lane * 8;
    const float4 a0 = *reinterpret_cast<const float4*>(ap);
    const float4 a1 = *reinterpret_cast<const float4*>(ap + 4);

    // ---- wave 3 computes ||batch[i]|| (usually same row -> L1 hit) ----
    if (wave == 3) {
        const float* __restrict__ rp = batch + (size_t)i * DD + lane * 8;
        const float4 r0 = *reinterpret_cast<const float4*>(rp);
        const float4 r1 = *reinterpret_cast<const float4*>(rp + 4);
        float s = r0.x*r0.x + r0.y*r0.y + r0.z*r0.z + r0.w*r0.w
                + r1.x*r1.x + r1.y*r1.y + r1.z*r1.z + r1.w*r1.w;
        s = wave_reduce_sum(s);
        if (lane == 0) norm_sh = sqrtf(s);
    }

    // ---- gather indices (block-uniform -> scalar loads) ----
    int idxs[PER_WAVE];
    #pragma unroll
    for (int t = 0; t < PER_WAVE; ++t) {
        const int j = wave * PER_WAVE + t;
        idxs[t] = (j < PP) ? pos_idx[i * PP + j] : neg_idx[i * QQ + (j - PP)];
    }

    // ---- issue ALL 20 float4 gathers before any use (10 rows in flight) ----
    float4 b0[PER_WAVE], b1[PER_WAVE];
    #pragma unroll
    for (int t = 0; t < PER_WAVE; ++t) {
        const float* __restrict__ bp = batch + (size_t)idxs[t] * DD + lane * 8;
        b0[t] = *reinterpret_cast<const float4*>(bp);
        b1[t] = *reinterpret_cast<const float4*>(bp + 4);
    }

    // ---- per-lane partial squared distances ----
    float s[PER_WAVE];
    #pragma unroll
    for (int t = 0; t < PER_WAVE; ++t) {
        float d, acc = 0.0f;
        d = a0.x - b0[t].x + EPS; acc += d * d;
        d = a0.y - b0[t].y + EPS; acc += d * d;
        d = a0.z - b0[t].z + EPS; acc += d * d;
        d = a0.w - b0[t].w + EPS; acc += d * d;
        d = a1.x - b1[t].x + EPS; acc += d * d;
        d = a1.y - b1[t].y + EPS; acc += d * d;
        d = a1.z - b1[t].z + EPS; acc += d * d;
        d = a1.w - b1[t].w + EPS; acc += d * d;
        s[t] = acc;
    }

    // ---- 10 independent shuffle-reduce chains (pipelined) ----
    #pragma unroll
    for (int t = 0; t < PER_WAVE; ++t) s[t] = wave_reduce_sum(s[t]);

    if (lane == 0) {
        #pragma unroll
        for (int t = 0; t < PER_WAVE; ++t)
            dist[wave * PER_WAVE + t] = sqrtf(s[t]);
    }

    __syncthreads();

    // ---- wave-parallel logsumexp epilogue (lanes 0..39 active) ----
    if (wave == 0) {
        const float d = (lane < NB_TOT) ? dist[lane] : 0.0f;

        // pos logsumexp over lanes 0..7
        const bool pact = (lane < PP);
        const float pm = wave_reduce_max(pact ? d : -FLT_MAX);
        const float ps = wave_reduce_sum(pact ? expf(d - pm) : 0.0f);
        const float pos_term = pm + logf(ps);

        // neg logsumexp over lanes 8..39 of (MARGIN - d)
        const bool nact = (lane >= PP) && (lane < NB_TOT);
        const float nv = MARGIN - d;
        const float nm = wave_reduce_max(nact ? nv : -FLT_MAX);
        const float ns = wave_reduce_sum(nact ? expf(nv - nm) : 0.0f);
        const float neg_term = nm + logf(ns);

        if (lane == 0)
            ws[i] = fmaxf(0.0f, pos_term + neg_term) + L2W * norm_sh;
    }
}

// Single-block final reduction: out = mean(ws[0..N))
__global__ __launch_bounds__(256) void reduce_kernel(
    const float* __restrict__ ws, float* __restrict__ out)
{
    const int tid  = threadIdx.x;
    const int lane = tid & 63;
    const int wave = tid >> 6;

    const float4* __restrict__ w4 = reinterpret_cast<const float4*>(ws);
    float s = 0.0f;
    #pragma unroll
    for (int k = 0; k < 4; ++k) {          // 1024 float4 total
        const float4 v = w4[tid + 256 * k];
        s += v.x + v.y + v.z + v.w;
    }
    s = wave_reduce_sum(s);

    __shared__ float part[4];
    if (lane == 0) part[wave] = s;
    __syncthreads();
    if (tid == 0)
        out[0] = (part[0] + part[1] + part[2] + part[3]) * (1.0f / (float)NN);
}

extern "C" void kernel_launch(void* const* d_in, const int* in_sizes, int n_in,
                              void* d_out, int out_size, void* d_ws, size_t ws_size,
                              hipStream_t stream) {
    const float* batch   = (const float*)d_in[0];
    const int*   anchors = (const int*)d_in[1];
    const int*   pos_idx = (const int*)d_in[2];
    const int*   neg_idx = (const int*)d_in[3];
    float*       ws      = (float*)d_ws;
    float*       out     = (float*)d_out;

    dist_kernel<<<NN, 256, 0, stream>>>(batch, anchors, pos_idx, neg_idx, ws);
    reduce_kernel<<<1, 256, 0, stream>>>(ws, out);
}